// Round 19
// baseline (2246.391 us; speedup 1.0000x reference)
//
#include <hip/hip_runtime.h>
#include <math.h>

#define B 64
#define N 196
#define E 2048
#define D 512
#define AA 512
#define EM 512
#define V 10000
#define TSTEPS 20
#define XC 3072          // xcat: [inp(512) | awe(2048) | h(512)]
#define HOFF 2560
#define AGW 2560         // [att2(512) | gate(2048)]
#define AGS 4            // split-K slices for att2|gate (K=512 -> 128)
#define ZS1 8            // split-K slices for W_ih (K=2560 -> 320)
#define ZS2 4            // split-K slices for W_hh (K=512 -> 128)
#define PS 2             // split-K slices for preds (K=512 -> 256)
#define ATT1_ELEMS ((size_t)B * N * AA)   // 6422528
#define M_ROWS (B * N)
#define KT (E / 16)                       // 128

typedef _Float16 f16x4 __attribute__((ext_vector_type(4)));
typedef float f32x4v __attribute__((ext_vector_type(4)));

__device__ __forceinline__ float sigmoidf_(float x) { return 1.0f / (1.0f + expf(-x)); }

__device__ __forceinline__ float4 ldg4_guard(const float* __restrict__ wp, int n, int Nn) {
    if (n + 3 < Nn) return *(const float4*)&wp[n];
    float4 bv;
    bv.x = (n     < Nn) ? wp[n]     : 0.f;
    bv.y = (n + 1 < Nn) ? wp[n + 1] : 0.f;
    bv.z = (n + 2 < Nn) ? wp[n + 2] : 0.f;
    bv.w = (n + 3 < Nn) ? wp[n + 3] : 0.f;
    return bv;
}

__device__ __forceinline__ void split4(float4 v, f16x4& h, f16x4& lo) {
    h[0] = (_Float16)v.x; lo[0] = (_Float16)(v.x - (float)h[0]);
    h[1] = (_Float16)v.y; lo[1] = (_Float16)(v.y - (float)h[1]);
    h[2] = (_Float16)v.z; lo[2] = (_Float16)(v.z - (float)h[2]);
    h[3] = (_Float16)v.w; lo[3] = (_Float16)(v.w - (float)h[3]);
}

// ---------------- mean over N ----------------
__global__ __launch_bounds__(256) void k_mean(const float* __restrict__ feat,
                                              float* __restrict__ mean_enc) {
    int i = blockIdx.x * 256 + threadIdx.x;
    int b = i >> 11, e = i & (E - 1);
    const float* p = feat + (size_t)b * N * E + e;
    float s = 0.f;
    for (int n = 0; n < N; ++n) s += p[(size_t)n * E];
    mean_enc[i] = s * (1.0f / (float)N);
}

// ---------------- h,c init ----------------
__global__ __launch_bounds__(256) void k_init_hc(const float* __restrict__ me,
                                                 const float* __restrict__ Wh, const float* __restrict__ bh,
                                                 const float* __restrict__ Wc, const float* __restrict__ bc,
                                                 float* __restrict__ xcat, float* __restrict__ c) {
    int i = blockIdx.x * 256 + threadIdx.x;
    int b = i >> 9, d = i & (D - 1);
    const float* m = me + (size_t)b * E;
    float ha = bh[d], ca = bc[d];
    for (int e = 0; e < E; ++e) {
        float mv = m[e];
        ha += mv * Wh[(size_t)e * D + d];
        ca += mv * Wc[(size_t)e * D + d];
    }
    xcat[(size_t)b * XC + HOFF + d] = ha;
    c[i] = ca;
}

// ---------------- inp = embedding[1] ----------------
__global__ __launch_bounds__(256) void k_init_inp(const float* __restrict__ emb,
                                                  float* __restrict__ xcat) {
    int i = blockIdx.x * 256 + threadIdx.x;
    int b = i >> 9, k = i & (EM - 1);
    xcat[(size_t)b * XC + k] = emb[EM + k];
}

// ---------------- pack A (feat) frag-order f16 hi/lo (r14-verified) ----------------
__global__ __launch_bounds__(256) void k_packA2(const float* __restrict__ feat,
                                                _Float16* __restrict__ Ah2,
                                                _Float16* __restrict__ Al2) {
    int i = blockIdx.x * 256 + threadIdx.x;
    int l = i & 63, kt = (i >> 6) & (KT - 1), rt = i >> 13;
    int lr = l & 15, lk = l >> 4;
    float4 v = *(const float4*)&feat[(size_t)(rt * 16 + lr) * E + kt * 16 + 4 * lk];
    f16x4 h, lo;
    split4(v, h, lo);
    *(f16x4*)&Ah2[(size_t)i * 4] = h;
    *(f16x4*)&Al2[(size_t)i * 4] = lo;
}

// ---------------- pack B (W_enc_att) frag-order (r14-verified) ----------------
__global__ __launch_bounds__(256) void k_packB2(const float* __restrict__ Wea,
                                                _Float16* __restrict__ Bh2,
                                                _Float16* __restrict__ Bl2) {
    int i = blockIdx.x * 256 + threadIdx.x;
    int l = i & 63, kt = (i >> 6) & (KT - 1), ct = i >> 13;
    int lr = l & 15, lk = l >> 4;
    int k = kt * 16 + 4 * lk, n = ct * 16 + lr;
    f16x4 h, lo;
    float4 v;
    v.x = Wea[(size_t)(k + 0) * AA + n];
    v.y = Wea[(size_t)(k + 1) * AA + n];
    v.z = Wea[(size_t)(k + 2) * AA + n];
    v.w = Wea[(size_t)(k + 3) * AA + n];
    split4(v, h, lo);
    *(f16x4*)&Bh2[(size_t)i * 4] = h;
    *(f16x4*)&Bl2[(size_t)i * 4] = lo;
}

// ---------------- att1 MFMA with SPLIT ACCUMULATORS ----------------
// r14-verified layouts; hi-term and lo-terms accumulate separately (acch 1-chain,
// accl 2-chain per kt) -> 16 independent MFMA chains/wave instead of 8x3-serial.
// Final C = acch + accl (fp32 adds; order change within fp32 noise, cf. dropped al*bl).
__global__ __launch_bounds__(256) void k_att1_mfma(const _Float16* __restrict__ Ah2,
                                                   const _Float16* __restrict__ Al2,
                                                   const _Float16* __restrict__ Bh2,
                                                   const _Float16* __restrict__ Bl2,
                                                   float* __restrict__ Cm) {
    int bid = blockIdx.x;
    int wg = (bid & 7) * 98 + (bid >> 3);
    int xt = wg >> 2, yc = wg & 3;
    int w = threadIdx.x >> 6, l = threadIdx.x & 63;
    int wr = w >> 1, wc = w & 1;
    int row0 = xt * 64 + wr * 32;
    int col0 = yc * 128 + wc * 64;
    int lr = l & 15, lk = l >> 4;
    int rt0 = xt * 4 + wr * 2, rt1 = rt0 + 1;
    int ct0 = yc * 8 + wc * 4;
    const f16x4* a0h = (const f16x4*)Ah2 + (size_t)rt0 * KT * 64 + l;
    const f16x4* a0l = (const f16x4*)Al2 + (size_t)rt0 * KT * 64 + l;
    const f16x4* a1h = (const f16x4*)Ah2 + (size_t)rt1 * KT * 64 + l;
    const f16x4* a1l = (const f16x4*)Al2 + (size_t)rt1 * KT * 64 + l;
    const f16x4* bhp[4]; const f16x4* blp[4];
#pragma unroll
    for (int ni = 0; ni < 4; ++ni) {
        bhp[ni] = (const f16x4*)Bh2 + (size_t)(ct0 + ni) * KT * 64 + l;
        blp[ni] = (const f16x4*)Bl2 + (size_t)(ct0 + ni) * KT * 64 + l;
    }
    f32x4v acch[2][4] = {};
    f32x4v accl[2][4] = {};
    f16x4 ah0, al0, ah1, al1, bh[4], bl[4];
    f16x4 nah0, nal0, nah1, nal1, nbh[4], nbl[4];
#define LOAD_FRAGS(kt, H0, L0, H1, L1, BH, BL)          \
    {                                                   \
        int off = (kt) * 64;                            \
        H0 = a0h[off]; L0 = a0l[off];                   \
        H1 = a1h[off]; L1 = a1l[off];                   \
        _Pragma("unroll")                               \
        for (int ni = 0; ni < 4; ++ni) {                \
            BH[ni] = bhp[ni][off];                      \
            BL[ni] = blp[ni][off];                      \
        }                                               \
    }
    LOAD_FRAGS(0, ah0, al0, ah1, al1, bh, bl)
    for (int kt = 0; kt < KT; ++kt) {
        if (kt + 1 < KT) {
            LOAD_FRAGS(kt + 1, nah0, nal0, nah1, nal1, nbh, nbl)
        }
#pragma unroll
        for (int ni = 0; ni < 4; ++ni) {
            acch[0][ni] = __builtin_amdgcn_mfma_f32_16x16x16f16(ah0, bh[ni], acch[0][ni], 0, 0, 0);
            accl[0][ni] = __builtin_amdgcn_mfma_f32_16x16x16f16(ah0, bl[ni], accl[0][ni], 0, 0, 0);
            accl[0][ni] = __builtin_amdgcn_mfma_f32_16x16x16f16(al0, bh[ni], accl[0][ni], 0, 0, 0);
            acch[1][ni] = __builtin_amdgcn_mfma_f32_16x16x16f16(ah1, bh[ni], acch[1][ni], 0, 0, 0);
            accl[1][ni] = __builtin_amdgcn_mfma_f32_16x16x16f16(ah1, bl[ni], accl[1][ni], 0, 0, 0);
            accl[1][ni] = __builtin_amdgcn_mfma_f32_16x16x16f16(al1, bh[ni], accl[1][ni], 0, 0, 0);
        }
        ah0 = nah0; al0 = nal0; ah1 = nah1; al1 = nal1;
#pragma unroll
        for (int ni = 0; ni < 4; ++ni) { bh[ni] = nbh[ni]; bl[ni] = nbl[ni]; }
    }
#undef LOAD_FRAGS
#pragma unroll
    for (int mi = 0; mi < 2; ++mi)
#pragma unroll
        for (int ni = 0; ni < 4; ++ni)
#pragma unroll
            for (int r = 0; r < 4; ++r)
                Cm[(size_t)(row0 + 16 * mi + lk * 4 + r) * AA + col0 + 16 * ni + lr] =
                    acch[mi][ni][r] + accl[mi][ni][r];
}

// ======== BK=32 fp32 GEMM inner body (r18-verified, shared by k_ag/k_z/k_preds) ========
#define GEMM32_BODY(A_EXPR, B_LOAD0, B_LOAD1)                                     \
    int tx = t & 15, ty = t >> 4;                                                 \
    int arow = t >> 2, ak8 = (t & 3) * 8;                                         \
    int bkr = t >> 3, bc8 = (t & 7) * 8;                                          \
    float4 pa0, pa1, pb0, pb1;                                                    \
    { int k0 = kbeg;                                                              \
      pa0 = *(const float4*)&(A_EXPR)[ak8];                                       \
      pa1 = *(const float4*)&(A_EXPR)[ak8 + 4];                                   \
      pb0 = B_LOAD0; pb1 = B_LOAD1; }                                             \
    float acc[4][4] = {};                                                         \
    for (int k0 = kbeg; k0 < kend; k0 += 32) {                                    \
        As[ak8 + 0][arow] = pa0.x; As[ak8 + 1][arow] = pa0.y;                     \
        As[ak8 + 2][arow] = pa0.z; As[ak8 + 3][arow] = pa0.w;                     \
        As[ak8 + 4][arow] = pa1.x; As[ak8 + 5][arow] = pa1.y;                     \
        As[ak8 + 6][arow] = pa1.z; As[ak8 + 7][arow] = pa1.w;                     \
        *(float4*)&Bs[bkr][bc8]     = pb0;                                        \
        *(float4*)&Bs[bkr][bc8 + 4] = pb1;                                        \
        __syncthreads();                                                          \
        if (k0 + 32 < kend) {                                                     \
            int k1 = k0 + 32;                                                     \
            pa0 = *(const float4*)&(A_EXPR2)[ak8];                                \
            pa1 = *(const float4*)&(A_EXPR2)[ak8 + 4];                            \
            pb0 = B_LOAD0N; pb1 = B_LOAD1N;                                       \
        }                                                                         \
        _Pragma("unroll")                                                         \
        for (int kk = 0; kk < 32; ++kk) {                                         \
            float4 a4 = *(const float4*)&As[kk][ty * 4];                          \
            float4 b4 = *(const float4*)&Bs[kk][tx * 4];                          \
            acc[0][0] += a4.x * b4.x; acc[0][1] += a4.x * b4.y; acc[0][2] += a4.x * b4.z; acc[0][3] += a4.x * b4.w; \
            acc[1][0] += a4.y * b4.x; acc[1][1] += a4.y * b4.y; acc[1][2] += a4.y * b4.z; acc[1][3] += a4.y * b4.w; \
            acc[2][0] += a4.z * b4.x; acc[2][1] += a4.z * b4.y; acc[2][2] += a4.z * b4.z; acc[2][3] += a4.z * b4.w; \
            acc[3][0] += a4.w * b4.x; acc[3][1] += a4.w * b4.y; acc[3][2] += a4.w * b4.z; acc[3][3] += a4.w * b4.w; \
        }                                                                         \
        __syncthreads();                                                          \
    }

// ---------------- att2|gate split-K fp32, BK=32 ----------------
__global__ __launch_bounds__(256) void k_ag(const float* __restrict__ xcat,
                                            const float* __restrict__ Wda,
                                            const float* __restrict__ Wfb,
                                            const float* __restrict__ bfb,
                                            float* __restrict__ agp) {
    __shared__ float As[32][68];
    __shared__ float Bs[32][64];
    int tile = blockIdx.x, slice = blockIdx.y;
    const float* W; const float* bias = nullptr; int ldw, n0, co;
    if (tile < 8) { W = Wda; ldw = AA; n0 = tile * 64;       co = n0; }
    else          { W = Wfb; ldw = E;  n0 = (tile - 8) * 64; co = AA + n0;
                    if (slice == 0) bias = bfb; }
    float* ag = agp + (size_t)slice * B * AGW;
    int kbeg = slice * (D / AGS), kend = kbeg + D / AGS;
    const float* Abase = xcat + HOFF;
    int t = threadIdx.x;
#define A_EXPR  (&Abase[(size_t)arow * XC + k0])
#define A_EXPR2 (&Abase[(size_t)arow * XC + k1])
#define B_LOAD0  (*(const float4*)&W[(size_t)(k0 + bkr) * ldw + n0 + bc8])
#define B_LOAD1  (*(const float4*)&W[(size_t)(k0 + bkr) * ldw + n0 + bc8 + 4])
#define B_LOAD0N (*(const float4*)&W[(size_t)(k1 + bkr) * ldw + n0 + bc8])
#define B_LOAD1N (*(const float4*)&W[(size_t)(k1 + bkr) * ldw + n0 + bc8 + 4])
    GEMM32_BODY(A_EXPR, B_LOAD0, B_LOAD1)
#undef A_EXPR
#undef A_EXPR2
#undef B_LOAD0
#undef B_LOAD1
#undef B_LOAD0N
#undef B_LOAD1N
#pragma unroll
    for (int i = 0; i < 4; ++i) {
        int row = ty * 4 + i;
#pragma unroll
        for (int j = 0; j < 4; ++j) {
            float v = acc[i][j];
            if (bias) v += bias[n0 + tx * 4 + j];
            ag[(size_t)row * AGW + co + tx * 4 + j] = v;
        }
    }
}

// ---------------- scores: wave per (b,n) row ----------------
__global__ __launch_bounds__(256) void k_scores(const float* __restrict__ att1,
                                                const float* __restrict__ agp,
                                                const float* __restrict__ wfull,
                                                float* __restrict__ scores) {
    int wid = threadIdx.x >> 6, lane = threadIdx.x & 63;
    int bn = blockIdx.x * 4 + wid;
    int b = bn / N;
    const float* a1 = att1 + (size_t)bn * AA;
    const float* a2 = agp + (size_t)b * AGW;
    const size_t SL = (size_t)B * AGW;
    float s = 0.f;
#pragma unroll
    for (int i = 0; i < AA / 256; ++i) {
        int a = i * 256 + lane * 4;
        float4 v  = *(const float4*)&a1[a];
        float4 p0 = *(const float4*)&a2[a];
        float4 p1 = *(const float4*)&a2[SL + a];
        float4 p2 = *(const float4*)&a2[2 * SL + a];
        float4 p3 = *(const float4*)&a2[3 * SL + a];
        float4 wf = *(const float4*)&wfull[a];
        s += fmaxf(v.x + p0.x + p1.x + p2.x + p3.x, 0.f) * wf.x;
        s += fmaxf(v.y + p0.y + p1.y + p2.y + p3.y, 0.f) * wf.y;
        s += fmaxf(v.z + p0.z + p1.z + p2.z + p3.z, 0.f) * wf.z;
        s += fmaxf(v.w + p0.w + p1.w + p2.w + p3.w, 0.f) * wf.w;
    }
    for (int off = 32; off; off >>= 1) s += __shfl_down(s, off);
    if (lane == 0) scores[bn] = s;
}

// ---------------- awe: in-block softmax + float4 weighted sum + gate ----------------
__global__ __launch_bounds__(256) void k_awe(const float* __restrict__ scores,
                                             const float* __restrict__ feat,
                                             const float* __restrict__ agp,
                                             float* __restrict__ xcat) {
    __shared__ float al[N];
    __shared__ float red[256];
    int b = blockIdx.y, ch = blockIdx.x, t = threadIdx.x;
    float v = (t < N) ? scores[b * N + t] : -INFINITY;
    red[t] = v; __syncthreads();
    for (int s = 128; s; s >>= 1) { if (t < s) red[t] = fmaxf(red[t], red[t + s]); __syncthreads(); }
    float mx = red[0]; __syncthreads();
    float e = (t < N) ? expf(v - mx) : 0.f;
    red[t] = e; __syncthreads();
    for (int s = 128; s; s >>= 1) { if (t < s) red[t] += red[t + s]; __syncthreads(); }
    float inv = 1.0f / red[0];
    if (t < N) al[t] = e * inv;
    __syncthreads();
    int e0 = ch * 1024 + t * 4;
    const float* f = feat + (size_t)b * N * E + e0;
    float4 s4 = {0.f, 0.f, 0.f, 0.f};
    for (int n = 0; n < N; n += 2) {
        float a0 = al[n], a1v = al[n + 1];
        float4 f0 = *(const float4*)f;
        float4 f1 = *(const float4*)(f + E);
        s4.x += a0 * f0.x + a1v * f1.x;
        s4.y += a0 * f0.y + a1v * f1.y;
        s4.z += a0 * f0.z + a1v * f1.z;
        s4.w += a0 * f0.w + a1v * f1.w;
        f += (size_t)2 * E;
    }
    const float* gp = agp + (size_t)b * AGW + AA + e0;
    const size_t SL = (size_t)B * AGW;
    float4 g0 = *(const float4*)&gp[0];
    float4 g1 = *(const float4*)&gp[SL];
    float4 g2 = *(const float4*)&gp[2 * SL];
    float4 g3 = *(const float4*)&gp[3 * SL];
    float4 o;
    o.x = s4.x * sigmoidf_(g0.x + g1.x + g2.x + g3.x);
    o.y = s4.y * sigmoidf_(g0.y + g1.y + g2.y + g3.y);
    o.z = s4.z * sigmoidf_(g0.z + g1.z + g2.z + g3.z);
    o.w = s4.w * sigmoidf_(g0.w + g1.w + g2.w + g3.w);
    *(float4*)&xcat[(size_t)b * XC + EM + e0] = o;
}

// ---------------- z partials fp32, BK=32: grid (32, 12) ----------------
__global__ __launch_bounds__(256) void k_z(const float* __restrict__ xcat,
                                           const float* __restrict__ Wih,
                                           const float* __restrict__ Whh,
                                           float* __restrict__ zpart) {
    __shared__ float As[32][68];
    __shared__ float Bs[32][64];
    int slice = blockIdx.y;
    const float* Abase; const float* W; int kbeg, kspan;
    if (slice < ZS1) { Abase = xcat;        W = Wih; kbeg = slice * ((EM + E) / ZS1); kspan = (EM + E) / ZS1; }
    else             { Abase = xcat + HOFF; W = Whh; kbeg = (slice - ZS1) * (D / ZS2); kspan = D / ZS2; }
    int kend = kbeg + kspan;
    float* C = zpart + (size_t)slice * B * 4 * D;
    int n0 = blockIdx.x * 64;
    int t = threadIdx.x;
#define A_EXPR  (&Abase[(size_t)arow * XC + k0])
#define A_EXPR2 (&Abase[(size_t)arow * XC + k1])
#define B_LOAD0  (*(const float4*)&W[(size_t)(k0 + bkr) * (4 * D) + n0 + bc8])
#define B_LOAD1  (*(const float4*)&W[(size_t)(k0 + bkr) * (4 * D) + n0 + bc8 + 4])
#define B_LOAD0N (*(const float4*)&W[(size_t)(k1 + bkr) * (4 * D) + n0 + bc8])
#define B_LOAD1N (*(const float4*)&W[(size_t)(k1 + bkr) * (4 * D) + n0 + bc8 + 4])
    GEMM32_BODY(A_EXPR, B_LOAD0, B_LOAD1)
#undef A_EXPR
#undef A_EXPR2
#undef B_LOAD0
#undef B_LOAD1
#undef B_LOAD0N
#undef B_LOAD1N
#pragma unroll
    for (int i = 0; i < 4; ++i) {
        int row = ty * 4 + i;
#pragma unroll
        for (int j = 0; j < 4; ++j)
            C[(size_t)row * (4 * D) + n0 + tx * 4 + j] = acc[i][j];
    }
}

// ---------------- LSTM: reduce 12 zpart slices ----------------
__global__ __launch_bounds__(256) void k_lstm(const float* __restrict__ zpart,
                                              const float* __restrict__ blstm,
                                              float* __restrict__ c,
                                              float* __restrict__ xcat) {
    int i4 = blockIdx.x * 256 + threadIdx.x;
    int b = i4 >> 7;
    int d4 = (i4 & 127) << 2;
    const float* zp = zpart + (size_t)b * (4 * D);
    float4 zi = *(const float4*)&blstm[d4];
    float4 zf = *(const float4*)&blstm[D + d4];
    float4 zg = *(const float4*)&blstm[2 * D + d4];
    float4 zo = *(const float4*)&blstm[3 * D + d4];
#pragma unroll
    for (int s = 0; s < ZS1 + ZS2; ++s) {
        const float* p = zp + (size_t)s * B * 4 * D;
        float4 a = *(const float4*)&p[d4];
        float4 bb = *(const float4*)&p[D + d4];
        float4 g = *(const float4*)&p[2 * D + d4];
        float4 o = *(const float4*)&p[3 * D + d4];
        zi.x += a.x; zi.y += a.y; zi.z += a.z; zi.w += a.w;
        zf.x += bb.x; zf.y += bb.y; zf.z += bb.z; zf.w += bb.w;
        zg.x += g.x; zg.y += g.y; zg.z += g.z; zg.w += g.w;
        zo.x += o.x; zo.y += o.y; zo.z += o.z; zo.w += o.w;
    }
    float4 cv = *(float4*)&c[(size_t)b * D + d4];
    float4 hv;
#define LSTM1(comp) { \
        float cn = sigmoidf_(zf.comp) * cv.comp + sigmoidf_(zi.comp) * tanhf(zg.comp); \
        cv.comp = cn; hv.comp = sigmoidf_(zo.comp) * tanhf(cn); }
    LSTM1(x) LSTM1(y) LSTM1(z) LSTM1(w)
#undef LSTM1
    *(float4*)&c[(size_t)b * D + d4] = cv;
    *(float4*)&xcat[(size_t)b * XC + HOFF + d4] = hv;
}

// ---------------- preds split-K fp32, BK=32: grid (157, PS=2) ----------------
__global__ __launch_bounds__(256) void k_preds(const float* __restrict__ xcat,
                                               const float* __restrict__ Wfc,
                                               const float* __restrict__ bfc,
                                               float* __restrict__ predsp) {
    __shared__ float As[32][68];
    __shared__ float Bs[32][64];
    int slice = blockIdx.y;
    int kbeg = slice * (D / PS), kend = kbeg + D / PS;
    float* preds = predsp + (size_t)slice * B * V;
    const float* bias = (slice == 0) ? bfc : nullptr;
    const float* Abase = xcat + HOFF;
    int n0 = blockIdx.x * 64;
    int t = threadIdx.x;
#define A_EXPR  (&Abase[(size_t)arow * XC + k0])
#define A_EXPR2 (&Abase[(size_t)arow * XC + k1])
#define B_LOAD0  ldg4_guard(&Wfc[(size_t)(k0 + bkr) * V], n0 + bc8, V)
#define B_LOAD1  ldg4_guard(&Wfc[(size_t)(k0 + bkr) * V], n0 + bc8 + 4, V)
#define B_LOAD0N ldg4_guard(&Wfc[(size_t)(k1 + bkr) * V], n0 + bc8, V)
#define B_LOAD1N ldg4_guard(&Wfc[(size_t)(k1 + bkr) * V], n0 + bc8 + 4, V)
    GEMM32_BODY(A_EXPR, B_LOAD0, B_LOAD1)
#undef A_EXPR
#undef A_EXPR2
#undef B_LOAD0
#undef B_LOAD1
#undef B_LOAD0N
#undef B_LOAD1N
#pragma unroll
    for (int i = 0; i < 4; ++i) {
        int row = ty * 4 + i;
#pragma unroll
        for (int j = 0; j < 4; ++j) {
            int col = n0 + tx * 4 + j;
            if (col < V) {
                float v = acc[i][j];
                if (bias) v += bias[col];
                preds[(size_t)row * V + col] = v;
            }
        }
    }
}

// ---------------- argmax (sums PS=2 partials) ----------------
__global__ __launch_bounds__(256) void k_argmax(const float* __restrict__ predsp,
                                                const float* __restrict__ emb,
                                                float* __restrict__ xcat,
                                                int* __restrict__ out,
                                                int step) {
    __shared__ float vals[256];
    __shared__ int idxs[256];
    __shared__ int pid_sh;
    int b = blockIdx.x, t = threadIdx.x;
    const float* p0 = predsp + (size_t)b * V;
    const float* p1 = predsp + (size_t)B * V + (size_t)b * V;
    float best = -INFINITY; int bi = 0;
    for (int v = t; v < V; v += 256) {
        float pv = p0[v] + p1[v];
        if (pv > best) { best = pv; bi = v; }
    }
    vals[t] = best; idxs[t] = bi; __syncthreads();
    for (int s = 128; s; s >>= 1) {
        if (t < s) {
            float ov = vals[t + s]; int oi = idxs[t + s];
            if (ov > vals[t] || (ov == vals[t] && oi < idxs[t])) { vals[t] = ov; idxs[t] = oi; }
        }
        __syncthreads();
    }
    if (t == 0) { pid_sh = idxs[0]; out[b * TSTEPS + step] = idxs[0]; }
    __syncthreads();
    int pid = pid_sh;
    for (int k = t; k < EM; k += 256) xcat[(size_t)b * XC + k] = emb[(size_t)pid * EM + k];
}

extern "C" void kernel_launch(void* const* d_in, const int* in_sizes, int n_in,
                              void* d_out, int out_size, void* d_ws, size_t ws_size,
                              hipStream_t stream) {
    const float* feat   = (const float*)d_in[0];
    const float* emb    = (const float*)d_in[1];
    const float* Wea    = (const float*)d_in[2];
    const float* Wda    = (const float*)d_in[3];
    const float* wfull  = (const float*)d_in[4];
    const float* Wih_   = (const float*)d_in[5];
    const float* bih    = (const float*)d_in[6];
    const float* Wic    = (const float*)d_in[7];
    const float* bic    = (const float*)d_in[8];
    const float* Wfb    = (const float*)d_in[9];
    const float* bfb    = (const float*)d_in[10];
    const float* Wih    = (const float*)d_in[11];
    const float* Whh    = (const float*)d_in[12];
    const float* blstm  = (const float*)d_in[13];
    const float* Wfc    = (const float*)d_in[14];
    const float* bfc    = (const float*)d_in[15];
    int* out = (int*)d_out;

    float* ws = (float*)d_ws;
    float* mean_enc = ws;                               // 131,072
    float* c        = mean_enc + (size_t)B * E;         // 32,768
    float* agp      = c + (size_t)B * D;                // 655,360
    float* scores   = agp + (size_t)AGS * B * AGW;      // 12,544
    float* xcat     = scores + (size_t)B * N;           // 196,608
    float* att1     = xcat + (size_t)B * XC;            // 6,422,528
    _Float16* Bh2   = (_Float16*)(att1 + ATT1_ELEMS);   // 1,048,576 halves
    _Float16* Bl2   = Bh2 + (size_t)AA * E;             // 1,048,576 halves
    // Region R: att1 A-packs (one-time), then REUSED for zpart/predsp (r16-proven aliasing)
    _Float16* Ah2   = Bl2 + (size_t)AA * E;             // 25,690,112 halves
    _Float16* Al2   = Ah2 + (size_t)M_ROWS * E;         // 25,690,112 halves
    float* zpart    = (float*)Ah2;                      // 12 x 131,072 floats
    float* predsp   = zpart + (size_t)(ZS1 + ZS2) * B * 4 * D;  // 2 x 640,000 floats
    // total ~137 MB (< 148 MB proven)

    // ---- one-time ----
    k_mean<<<(B * E) / 256, 256, 0, stream>>>(feat, mean_enc);
    k_init_hc<<<(B * D) / 256, 256, 0, stream>>>(mean_enc, Wih_, bih, Wic, bic, xcat, c);
    k_init_inp<<<(B * EM) / 256, 256, 0, stream>>>(emb, xcat);
    k_packB2<<<(32 * KT * 64) / 256, 256, 0, stream>>>(Wea, Bh2, Bl2);
    k_packA2<<<((M_ROWS / 16) * KT * 64) / 256, 256, 0, stream>>>(feat, Ah2, Al2);
    k_att1_mfma<<<(M_ROWS / 64) * (AA / 128), 256, 0, stream>>>(Ah2, Al2, Bh2, Bl2, att1);

    for (int t = 0; t < TSTEPS; ++t) {
        k_ag<<<dim3(40, AGS), 256, 0, stream>>>(xcat, Wda, Wfb, bfb, agp);
        k_scores<<<(B * N) / 4, 256, 0, stream>>>(att1, agp, wfull, scores);
        k_awe<<<dim3(E / 1024, B), 256, 0, stream>>>(scores, feat, agp, xcat);
        k_z<<<dim3((4 * D) / 64, ZS1 + ZS2), 256, 0, stream>>>(xcat, Wih, Whh, zpart);
        k_lstm<<<(B * D / 4) / 256, 256, 0, stream>>>(zpart, blstm, c, xcat);
        k_preds<<<dim3((V + 63) / 64, PS), 256, 0, stream>>>(xcat, Wfc, bfc, predsp);
        k_argmax<<<B, 256, 0, stream>>>(predsp, emb, xcat, out, t);
    }
}

// Round 20
// 2211.307 us; speedup vs baseline: 1.0159x; 1.0159x over previous
//
#include <hip/hip_runtime.h>
#include <math.h>

#define B 64
#define N 196
#define E 2048
#define D 512
#define AA 512
#define EM 512
#define V 10000
#define TSTEPS 20
#define XC 3072          // xcat: [inp(512) | awe(2048) | h(512)]
#define HOFF 2560
#define AGW 2560         // [att2(512) | gate(2048)]
#define AGS 4            // split-K slices for att2|gate (K=512 -> 128)
#define ZS1 8            // split-K slices for W_ih (K=2560 -> 320)
#define ZS2 4            // split-K slices for W_hh (K=512 -> 128)
#define PS 2             // split-K slices for preds (K=512 -> 256)
#define ATT1_ELEMS ((size_t)B * N * AA)   // 6422528
#define M_ROWS (B * N)
#define KT (E / 16)                       // 128

typedef _Float16 f16x4 __attribute__((ext_vector_type(4)));
typedef float f32x4v __attribute__((ext_vector_type(4)));

__device__ __forceinline__ float sigmoidf_(float x) { return 1.0f / (1.0f + expf(-x)); }

__device__ __forceinline__ float4 ldg4_guard(const float* __restrict__ wp, int n, int Nn) {
    if (n + 3 < Nn) return *(const float4*)&wp[n];
    float4 bv;
    bv.x = (n     < Nn) ? wp[n]     : 0.f;
    bv.y = (n + 1 < Nn) ? wp[n + 1] : 0.f;
    bv.z = (n + 2 < Nn) ? wp[n + 2] : 0.f;
    bv.w = (n + 3 < Nn) ? wp[n + 3] : 0.f;
    return bv;
}

__device__ __forceinline__ void split4(float4 v, f16x4& h, f16x4& lo) {
    h[0] = (_Float16)v.x; lo[0] = (_Float16)(v.x - (float)h[0]);
    h[1] = (_Float16)v.y; lo[1] = (_Float16)(v.y - (float)h[1]);
    h[2] = (_Float16)v.z; lo[2] = (_Float16)(v.z - (float)h[2]);
    h[3] = (_Float16)v.w; lo[3] = (_Float16)(v.w - (float)h[3]);
}

// ---------------- mean over N ----------------
__global__ __launch_bounds__(256) void k_mean(const float* __restrict__ feat,
                                              float* __restrict__ mean_enc) {
    int i = blockIdx.x * 256 + threadIdx.x;
    int b = i >> 11, e = i & (E - 1);
    const float* p = feat + (size_t)b * N * E + e;
    float s = 0.f;
    for (int n = 0; n < N; ++n) s += p[(size_t)n * E];
    mean_enc[i] = s * (1.0f / (float)N);
}

// ---------------- h,c init ----------------
__global__ __launch_bounds__(256) void k_init_hc(const float* __restrict__ me,
                                                 const float* __restrict__ Wh, const float* __restrict__ bh,
                                                 const float* __restrict__ Wc, const float* __restrict__ bc,
                                                 float* __restrict__ xcat, float* __restrict__ c) {
    int i = blockIdx.x * 256 + threadIdx.x;
    int b = i >> 9, d = i & (D - 1);
    const float* m = me + (size_t)b * E;
    float ha = bh[d], ca = bc[d];
    for (int e = 0; e < E; ++e) {
        float mv = m[e];
        ha += mv * Wh[(size_t)e * D + d];
        ca += mv * Wc[(size_t)e * D + d];
    }
    xcat[(size_t)b * XC + HOFF + d] = ha;
    c[i] = ca;
}

// ---------------- inp = embedding[1] ----------------
__global__ __launch_bounds__(256) void k_init_inp(const float* __restrict__ emb,
                                                  float* __restrict__ xcat) {
    int i = blockIdx.x * 256 + threadIdx.x;
    int b = i >> 9, k = i & (EM - 1);
    xcat[(size_t)b * XC + k] = emb[EM + k];
}

// ---------------- pack A (feat) frag-order f16 hi/lo (r14-verified) ----------------
__global__ __launch_bounds__(256) void k_packA2(const float* __restrict__ feat,
                                                _Float16* __restrict__ Ah2,
                                                _Float16* __restrict__ Al2) {
    int i = blockIdx.x * 256 + threadIdx.x;
    int l = i & 63, kt = (i >> 6) & (KT - 1), rt = i >> 13;
    int lr = l & 15, lk = l >> 4;
    float4 v = *(const float4*)&feat[(size_t)(rt * 16 + lr) * E + kt * 16 + 4 * lk];
    f16x4 h, lo;
    split4(v, h, lo);
    *(f16x4*)&Ah2[(size_t)i * 4] = h;
    *(f16x4*)&Al2[(size_t)i * 4] = lo;
}

// ---------------- pack B (W_enc_att) frag-order (r14-verified) ----------------
__global__ __launch_bounds__(256) void k_packB2(const float* __restrict__ Wea,
                                                _Float16* __restrict__ Bh2,
                                                _Float16* __restrict__ Bl2) {
    int i = blockIdx.x * 256 + threadIdx.x;
    int l = i & 63, kt = (i >> 6) & (KT - 1), ct = i >> 13;
    int lr = l & 15, lk = l >> 4;
    int k = kt * 16 + 4 * lk, n = ct * 16 + lr;
    f16x4 h, lo;
    float4 v;
    v.x = Wea[(size_t)(k + 0) * AA + n];
    v.y = Wea[(size_t)(k + 1) * AA + n];
    v.z = Wea[(size_t)(k + 2) * AA + n];
    v.w = Wea[(size_t)(k + 3) * AA + n];
    split4(v, h, lo);
    *(f16x4*)&Bh2[(size_t)i * 4] = h;
    *(f16x4*)&Bl2[(size_t)i * 4] = lo;
}

// ---------------- att1 MFMA (r14/r17/r18-verified best: 3-term single accumulator) ----------
__global__ __launch_bounds__(256) void k_att1_mfma(const _Float16* __restrict__ Ah2,
                                                   const _Float16* __restrict__ Al2,
                                                   const _Float16* __restrict__ Bh2,
                                                   const _Float16* __restrict__ Bl2,
                                                   float* __restrict__ Cm) {
    int bid = blockIdx.x;
    int wg = (bid & 7) * 98 + (bid >> 3);
    int xt = wg >> 2, yc = wg & 3;
    int w = threadIdx.x >> 6, l = threadIdx.x & 63;
    int wr = w >> 1, wc = w & 1;
    int row0 = xt * 64 + wr * 32;
    int col0 = yc * 128 + wc * 64;
    int lr = l & 15, lk = l >> 4;
    int rt0 = xt * 4 + wr * 2, rt1 = rt0 + 1;
    int ct0 = yc * 8 + wc * 4;
    const f16x4* a0h = (const f16x4*)Ah2 + (size_t)rt0 * KT * 64 + l;
    const f16x4* a0l = (const f16x4*)Al2 + (size_t)rt0 * KT * 64 + l;
    const f16x4* a1h = (const f16x4*)Ah2 + (size_t)rt1 * KT * 64 + l;
    const f16x4* a1l = (const f16x4*)Al2 + (size_t)rt1 * KT * 64 + l;
    const f16x4* bhp[4]; const f16x4* blp[4];
#pragma unroll
    for (int ni = 0; ni < 4; ++ni) {
        bhp[ni] = (const f16x4*)Bh2 + (size_t)(ct0 + ni) * KT * 64 + l;
        blp[ni] = (const f16x4*)Bl2 + (size_t)(ct0 + ni) * KT * 64 + l;
    }
    f32x4v acc[2][4] = {};
    f16x4 ah0, al0, ah1, al1, bh[4], bl[4];
    f16x4 nah0, nal0, nah1, nal1, nbh[4], nbl[4];
#define LOAD_FRAGS(kt, H0, L0, H1, L1, BH, BL)          \
    {                                                   \
        int off = (kt) * 64;                            \
        H0 = a0h[off]; L0 = a0l[off];                   \
        H1 = a1h[off]; L1 = a1l[off];                   \
        _Pragma("unroll")                               \
        for (int ni = 0; ni < 4; ++ni) {                \
            BH[ni] = bhp[ni][off];                      \
            BL[ni] = blp[ni][off];                      \
        }                                               \
    }
    LOAD_FRAGS(0, ah0, al0, ah1, al1, bh, bl)
    for (int kt = 0; kt < KT; ++kt) {
        if (kt + 1 < KT) {
            LOAD_FRAGS(kt + 1, nah0, nal0, nah1, nal1, nbh, nbl)
        }
#pragma unroll
        for (int ni = 0; ni < 4; ++ni) {
            acc[0][ni] = __builtin_amdgcn_mfma_f32_16x16x16f16(ah0, bh[ni], acc[0][ni], 0, 0, 0);
            acc[0][ni] = __builtin_amdgcn_mfma_f32_16x16x16f16(ah0, bl[ni], acc[0][ni], 0, 0, 0);
            acc[0][ni] = __builtin_amdgcn_mfma_f32_16x16x16f16(al0, bh[ni], acc[0][ni], 0, 0, 0);
            acc[1][ni] = __builtin_amdgcn_mfma_f32_16x16x16f16(ah1, bh[ni], acc[1][ni], 0, 0, 0);
            acc[1][ni] = __builtin_amdgcn_mfma_f32_16x16x16f16(ah1, bl[ni], acc[1][ni], 0, 0, 0);
            acc[1][ni] = __builtin_amdgcn_mfma_f32_16x16x16f16(al1, bh[ni], acc[1][ni], 0, 0, 0);
        }
        ah0 = nah0; al0 = nal0; ah1 = nah1; al1 = nal1;
#pragma unroll
        for (int ni = 0; ni < 4; ++ni) { bh[ni] = nbh[ni]; bl[ni] = nbl[ni]; }
    }
#undef LOAD_FRAGS
#pragma unroll
    for (int mi = 0; mi < 2; ++mi)
#pragma unroll
        for (int ni = 0; ni < 4; ++ni)
#pragma unroll
            for (int r = 0; r < 4; ++r)
                Cm[(size_t)(row0 + 16 * mi + lk * 4 + r) * AA + col0 + 16 * ni + lr] = acc[mi][ni][r];
}

// ======== BK=32 fp32 GEMM inner body (r18-verified, shared by k_ag/k_z/k_preds) ========
#define GEMM32_BODY(A_EXPR, B_LOAD0, B_LOAD1)                                     \
    int tx = t & 15, ty = t >> 4;                                                 \
    int arow = t >> 2, ak8 = (t & 3) * 8;                                         \
    int bkr = t >> 3, bc8 = (t & 7) * 8;                                          \
    float4 pa0, pa1, pb0, pb1;                                                    \
    { int k0 = kbeg;                                                              \
      pa0 = *(const float4*)&(A_EXPR)[ak8];                                       \
      pa1 = *(const float4*)&(A_EXPR)[ak8 + 4];                                   \
      pb0 = B_LOAD0; pb1 = B_LOAD1; }                                             \
    float acc[4][4] = {};                                                         \
    for (int k0 = kbeg; k0 < kend; k0 += 32) {                                    \
        As[ak8 + 0][arow] = pa0.x; As[ak8 + 1][arow] = pa0.y;                     \
        As[ak8 + 2][arow] = pa0.z; As[ak8 + 3][arow] = pa0.w;                     \
        As[ak8 + 4][arow] = pa1.x; As[ak8 + 5][arow] = pa1.y;                     \
        As[ak8 + 6][arow] = pa1.z; As[ak8 + 7][arow] = pa1.w;                     \
        *(float4*)&Bs[bkr][bc8]     = pb0;                                        \
        *(float4*)&Bs[bkr][bc8 + 4] = pb1;                                        \
        __syncthreads();                                                          \
        if (k0 + 32 < kend) {                                                     \
            int k1 = k0 + 32;                                                     \
            pa0 = *(const float4*)&(A_EXPR2)[ak8];                                \
            pa1 = *(const float4*)&(A_EXPR2)[ak8 + 4];                            \
            pb0 = B_LOAD0N; pb1 = B_LOAD1N;                                       \
        }                                                                         \
        _Pragma("unroll")                                                         \
        for (int kk = 0; kk < 32; ++kk) {                                         \
            float4 a4 = *(const float4*)&As[kk][ty * 4];                          \
            float4 b4 = *(const float4*)&Bs[kk][tx * 4];                          \
            acc[0][0] += a4.x * b4.x; acc[0][1] += a4.x * b4.y; acc[0][2] += a4.x * b4.z; acc[0][3] += a4.x * b4.w; \
            acc[1][0] += a4.y * b4.x; acc[1][1] += a4.y * b4.y; acc[1][2] += a4.y * b4.z; acc[1][3] += a4.y * b4.w; \
            acc[2][0] += a4.z * b4.x; acc[2][1] += a4.z * b4.y; acc[2][2] += a4.z * b4.z; acc[2][3] += a4.z * b4.w; \
            acc[3][0] += a4.w * b4.x; acc[3][1] += a4.w * b4.y; acc[3][2] += a4.w * b4.z; acc[3][3] += a4.w * b4.w; \
        }                                                                         \
        __syncthreads();                                                          \
    }

// ---------------- att2|gate split-K fp32, BK=32 ----------------
__global__ __launch_bounds__(256) void k_ag(const float* __restrict__ xcat,
                                            const float* __restrict__ Wda,
                                            const float* __restrict__ Wfb,
                                            const float* __restrict__ bfb,
                                            float* __restrict__ agp) {
    __shared__ float As[32][68];
    __shared__ float Bs[32][64];
    int tile = blockIdx.x, slice = blockIdx.y;
    const float* W; const float* bias = nullptr; int ldw, n0, co;
    if (tile < 8) { W = Wda; ldw = AA; n0 = tile * 64;       co = n0; }
    else          { W = Wfb; ldw = E;  n0 = (tile - 8) * 64; co = AA + n0;
                    if (slice == 0) bias = bfb; }
    float* ag = agp + (size_t)slice * B * AGW;
    int kbeg = slice * (D / AGS), kend = kbeg + D / AGS;
    const float* Abase = xcat + HOFF;
    int t = threadIdx.x;
#define A_EXPR  (&Abase[(size_t)arow * XC + k0])
#define A_EXPR2 (&Abase[(size_t)arow * XC + k1])
#define B_LOAD0  (*(const float4*)&W[(size_t)(k0 + bkr) * ldw + n0 + bc8])
#define B_LOAD1  (*(const float4*)&W[(size_t)(k0 + bkr) * ldw + n0 + bc8 + 4])
#define B_LOAD0N (*(const float4*)&W[(size_t)(k1 + bkr) * ldw + n0 + bc8])
#define B_LOAD1N (*(const float4*)&W[(size_t)(k1 + bkr) * ldw + n0 + bc8 + 4])
    GEMM32_BODY(A_EXPR, B_LOAD0, B_LOAD1)
#undef A_EXPR
#undef A_EXPR2
#undef B_LOAD0
#undef B_LOAD1
#undef B_LOAD0N
#undef B_LOAD1N
#pragma unroll
    for (int i = 0; i < 4; ++i) {
        int row = ty * 4 + i;
#pragma unroll
        for (int j = 0; j < 4; ++j) {
            float v = acc[i][j];
            if (bias) v += bias[n0 + tx * 4 + j];
            ag[(size_t)row * AGW + co + tx * 4 + j] = v;
        }
    }
}

// ---------------- scores: wave per (b,n) row ----------------
__global__ __launch_bounds__(256) void k_scores(const float* __restrict__ att1,
                                                const float* __restrict__ agp,
                                                const float* __restrict__ wfull,
                                                float* __restrict__ scores) {
    int wid = threadIdx.x >> 6, lane = threadIdx.x & 63;
    int bn = blockIdx.x * 4 + wid;
    int b = bn / N;
    const float* a1 = att1 + (size_t)bn * AA;
    const float* a2 = agp + (size_t)b * AGW;
    const size_t SL = (size_t)B * AGW;
    float s = 0.f;
#pragma unroll
    for (int i = 0; i < AA / 256; ++i) {
        int a = i * 256 + lane * 4;
        float4 v  = *(const float4*)&a1[a];
        float4 p0 = *(const float4*)&a2[a];
        float4 p1 = *(const float4*)&a2[SL + a];
        float4 p2 = *(const float4*)&a2[2 * SL + a];
        float4 p3 = *(const float4*)&a2[3 * SL + a];
        float4 wf = *(const float4*)&wfull[a];
        s += fmaxf(v.x + p0.x + p1.x + p2.x + p3.x, 0.f) * wf.x;
        s += fmaxf(v.y + p0.y + p1.y + p2.y + p3.y, 0.f) * wf.y;
        s += fmaxf(v.z + p0.z + p1.z + p2.z + p3.z, 0.f) * wf.z;
        s += fmaxf(v.w + p0.w + p1.w + p2.w + p3.w, 0.f) * wf.w;
    }
    for (int off = 32; off; off >>= 1) s += __shfl_down(s, off);
    if (lane == 0) scores[bn] = s;
}

// ---------------- awe: in-block softmax + float4 weighted sum + gate ----------------
__global__ __launch_bounds__(256) void k_awe(const float* __restrict__ scores,
                                             const float* __restrict__ feat,
                                             const float* __restrict__ agp,
                                             float* __restrict__ xcat) {
    __shared__ float al[N];
    __shared__ float red[256];
    int b = blockIdx.y, ch = blockIdx.x, t = threadIdx.x;
    float v = (t < N) ? scores[b * N + t] : -INFINITY;
    red[t] = v; __syncthreads();
    for (int s = 128; s; s >>= 1) { if (t < s) red[t] = fmaxf(red[t], red[t + s]); __syncthreads(); }
    float mx = red[0]; __syncthreads();
    float e = (t < N) ? expf(v - mx) : 0.f;
    red[t] = e; __syncthreads();
    for (int s = 128; s; s >>= 1) { if (t < s) red[t] += red[t + s]; __syncthreads(); }
    float inv = 1.0f / red[0];
    if (t < N) al[t] = e * inv;
    __syncthreads();
    int e0 = ch * 1024 + t * 4;
    const float* f = feat + (size_t)b * N * E + e0;
    float4 s4 = {0.f, 0.f, 0.f, 0.f};
    for (int n = 0; n < N; n += 2) {
        float a0 = al[n], a1v = al[n + 1];
        float4 f0 = *(const float4*)f;
        float4 f1 = *(const float4*)(f + E);
        s4.x += a0 * f0.x + a1v * f1.x;
        s4.y += a0 * f0.y + a1v * f1.y;
        s4.z += a0 * f0.z + a1v * f1.z;
        s4.w += a0 * f0.w + a1v * f1.w;
        f += (size_t)2 * E;
    }
    const float* gp = agp + (size_t)b * AGW + AA + e0;
    const size_t SL = (size_t)B * AGW;
    float4 g0 = *(const float4*)&gp[0];
    float4 g1 = *(const float4*)&gp[SL];
    float4 g2 = *(const float4*)&gp[2 * SL];
    float4 g3 = *(const float4*)&gp[3 * SL];
    float4 o;
    o.x = s4.x * sigmoidf_(g0.x + g1.x + g2.x + g3.x);
    o.y = s4.y * sigmoidf_(g0.y + g1.y + g2.y + g3.y);
    o.z = s4.z * sigmoidf_(g0.z + g1.z + g2.z + g3.z);
    o.w = s4.w * sigmoidf_(g0.w + g1.w + g2.w + g3.w);
    *(float4*)&xcat[(size_t)b * XC + EM + e0] = o;
}

// ---------------- z partials fp32, BK=32: grid (32, 12) ----------------
__global__ __launch_bounds__(256) void k_z(const float* __restrict__ xcat,
                                           const float* __restrict__ Wih,
                                           const float* __restrict__ Whh,
                                           float* __restrict__ zpart) {
    __shared__ float As[32][68];
    __shared__ float Bs[32][64];
    int slice = blockIdx.y;
    const float* Abase; const float* W; int kbeg, kspan;
    if (slice < ZS1) { Abase = xcat;        W = Wih; kbeg = slice * ((EM + E) / ZS1); kspan = (EM + E) / ZS1; }
    else             { Abase = xcat + HOFF; W = Whh; kbeg = (slice - ZS1) * (D / ZS2); kspan = D / ZS2; }
    int kend = kbeg + kspan;
    float* C = zpart + (size_t)slice * B * 4 * D;
    int n0 = blockIdx.x * 64;
    int t = threadIdx.x;
#define A_EXPR  (&Abase[(size_t)arow * XC + k0])
#define A_EXPR2 (&Abase[(size_t)arow * XC + k1])
#define B_LOAD0  (*(const float4*)&W[(size_t)(k0 + bkr) * (4 * D) + n0 + bc8])
#define B_LOAD1  (*(const float4*)&W[(size_t)(k0 + bkr) * (4 * D) + n0 + bc8 + 4])
#define B_LOAD0N (*(const float4*)&W[(size_t)(k1 + bkr) * (4 * D) + n0 + bc8])
#define B_LOAD1N (*(const float4*)&W[(size_t)(k1 + bkr) * (4 * D) + n0 + bc8 + 4])
    GEMM32_BODY(A_EXPR, B_LOAD0, B_LOAD1)
#undef A_EXPR
#undef A_EXPR2
#undef B_LOAD0
#undef B_LOAD1
#undef B_LOAD0N
#undef B_LOAD1N
#pragma unroll
    for (int i = 0; i < 4; ++i) {
        int row = ty * 4 + i;
#pragma unroll
        for (int j = 0; j < 4; ++j)
            C[(size_t)row * (4 * D) + n0 + tx * 4 + j] = acc[i][j];
    }
}

// ---------------- LSTM: reduce 12 zpart slices ----------------
__global__ __launch_bounds__(256) void k_lstm(const float* __restrict__ zpart,
                                              const float* __restrict__ blstm,
                                              float* __restrict__ c,
                                              float* __restrict__ xcat) {
    int i4 = blockIdx.x * 256 + threadIdx.x;
    int b = i4 >> 7;
    int d4 = (i4 & 127) << 2;
    const float* zp = zpart + (size_t)b * (4 * D);
    float4 zi = *(const float4*)&blstm[d4];
    float4 zf = *(const float4*)&blstm[D + d4];
    float4 zg = *(const float4*)&blstm[2 * D + d4];
    float4 zo = *(const float4*)&blstm[3 * D + d4];
#pragma unroll
    for (int s = 0; s < ZS1 + ZS2; ++s) {
        const float* p = zp + (size_t)s * B * 4 * D;
        float4 a = *(const float4*)&p[d4];
        float4 bb = *(const float4*)&p[D + d4];
        float4 g = *(const float4*)&p[2 * D + d4];
        float4 o = *(const float4*)&p[3 * D + d4];
        zi.x += a.x; zi.y += a.y; zi.z += a.z; zi.w += a.w;
        zf.x += bb.x; zf.y += bb.y; zf.z += bb.z; zf.w += bb.w;
        zg.x += g.x; zg.y += g.y; zg.z += g.z; zg.w += g.w;
        zo.x += o.x; zo.y += o.y; zo.z += o.z; zo.w += o.w;
    }
    float4 cv = *(float4*)&c[(size_t)b * D + d4];
    float4 hv;
#define LSTM1(comp) { \
        float cn = sigmoidf_(zf.comp) * cv.comp + sigmoidf_(zi.comp) * tanhf(zg.comp); \
        cv.comp = cn; hv.comp = sigmoidf_(zo.comp) * tanhf(cn); }
    LSTM1(x) LSTM1(y) LSTM1(z) LSTM1(w)
#undef LSTM1
    *(float4*)&c[(size_t)b * D + d4] = cv;
    *(float4*)&xcat[(size_t)b * XC + HOFF + d4] = hv;
}

// ---------------- preds split-K fp32, BK=32: grid (157, PS=2) ----------------
__global__ __launch_bounds__(256) void k_preds(const float* __restrict__ xcat,
                                               const float* __restrict__ Wfc,
                                               const float* __restrict__ bfc,
                                               float* __restrict__ predsp) {
    __shared__ float As[32][68];
    __shared__ float Bs[32][64];
    int slice = blockIdx.y;
    int kbeg = slice * (D / PS), kend = kbeg + D / PS;
    float* preds = predsp + (size_t)slice * B * V;
    const float* bias = (slice == 0) ? bfc : nullptr;
    const float* Abase = xcat + HOFF;
    int n0 = blockIdx.x * 64;
    int t = threadIdx.x;
#define A_EXPR  (&Abase[(size_t)arow * XC + k0])
#define A_EXPR2 (&Abase[(size_t)arow * XC + k1])
#define B_LOAD0  ldg4_guard(&Wfc[(size_t)(k0 + bkr) * V], n0 + bc8, V)
#define B_LOAD1  ldg4_guard(&Wfc[(size_t)(k0 + bkr) * V], n0 + bc8 + 4, V)
#define B_LOAD0N ldg4_guard(&Wfc[(size_t)(k1 + bkr) * V], n0 + bc8, V)
#define B_LOAD1N ldg4_guard(&Wfc[(size_t)(k1 + bkr) * V], n0 + bc8 + 4, V)
    GEMM32_BODY(A_EXPR, B_LOAD0, B_LOAD1)
#undef A_EXPR
#undef A_EXPR2
#undef B_LOAD0
#undef B_LOAD1
#undef B_LOAD0N
#undef B_LOAD1N
#pragma unroll
    for (int i = 0; i < 4; ++i) {
        int row = ty * 4 + i;
#pragma unroll
        for (int j = 0; j < 4; ++j) {
            int col = n0 + tx * 4 + j;
            if (col < V) {
                float v = acc[i][j];
                if (bias) v += bias[col];
                preds[(size_t)row * V + col] = v;
            }
        }
    }
}

// ---------------- argmax (sums PS=2 partials) ----------------
__global__ __launch_bounds__(256) void k_argmax(const float* __restrict__ predsp,
                                                const float* __restrict__ emb,
                                                float* __restrict__ xcat,
                                                int* __restrict__ out,
                                                int step) {
    __shared__ float vals[256];
    __shared__ int idxs[256];
    __shared__ int pid_sh;
    int b = blockIdx.x, t = threadIdx.x;
    const float* p0 = predsp + (size_t)b * V;
    const float* p1 = predsp + (size_t)B * V + (size_t)b * V;
    float best = -INFINITY; int bi = 0;
    for (int v = t; v < V; v += 256) {
        float pv = p0[v] + p1[v];
        if (pv > best) { best = pv; bi = v; }
    }
    vals[t] = best; idxs[t] = bi; __syncthreads();
    for (int s = 128; s; s >>= 1) {
        if (t < s) {
            float ov = vals[t + s]; int oi = idxs[t + s];
            if (ov > vals[t] || (ov == vals[t] && oi < idxs[t])) { vals[t] = ov; idxs[t] = oi; }
        }
        __syncthreads();
    }
    if (t == 0) { pid_sh = idxs[0]; out[b * TSTEPS + step] = idxs[0]; }
    __syncthreads();
    int pid = pid_sh;
    for (int k = t; k < EM; k += 256) xcat[(size_t)b * XC + k] = emb[(size_t)pid * EM + k];
}

extern "C" void kernel_launch(void* const* d_in, const int* in_sizes, int n_in,
                              void* d_out, int out_size, void* d_ws, size_t ws_size,
                              hipStream_t stream) {
    const float* feat   = (const float*)d_in[0];
    const float* emb    = (const float*)d_in[1];
    const float* Wea    = (const float*)d_in[2];
    const float* Wda    = (const float*)d_in[3];
    const float* wfull  = (const float*)d_in[4];
    const float* Wih_   = (const float*)d_in[5];
    const float* bih    = (const float*)d_in[6];
    const float* Wic    = (const float*)d_in[7];
    const float* bic    = (const float*)d_in[8];
    const float* Wfb    = (const float*)d_in[9];
    const float* bfb    = (const float*)d_in[10];
    const float* Wih    = (const float*)d_in[11];
    const float* Whh    = (const float*)d_in[12];
    const float* blstm  = (const float*)d_in[13];
    const float* Wfc    = (const float*)d_in[14];
    const float* bfc    = (const float*)d_in[15];
    int* out = (int*)d_out;

    float* ws = (float*)d_ws;
    float* mean_enc = ws;                               // 131,072
    float* c        = mean_enc + (size_t)B * E;         // 32,768
    float* agp      = c + (size_t)B * D;                // 655,360
    float* scores   = agp + (size_t)AGS * B * AGW;      // 12,544
    float* xcat     = scores + (size_t)B * N;           // 196,608
    float* att1     = xcat + (size_t)B * XC;            // 6,422,528
    _Float16* Bh2   = (_Float16*)(att1 + ATT1_ELEMS);   // 1,048,576 halves
    _Float16* Bl2   = Bh2 + (size_t)AA * E;             // 1,048,576 halves
    // Region R: att1 A-packs (one-time), then REUSED for zpart/predsp (r16-proven aliasing)
    _Float16* Ah2   = Bl2 + (size_t)AA * E;             // 25,690,112 halves
    _Float16* Al2   = Ah2 + (size_t)M_ROWS * E;         // 25,690,112 halves
    float* zpart    = (float*)Ah2;                      // 12 x 131,072 floats
    float* predsp   = zpart + (size_t)(ZS1 + ZS2) * B * 4 * D;  // 2 x 640,000 floats
    // total ~137 MB (< 148 MB proven)

    // ---- one-time ----
    k_mean<<<(B * E) / 256, 256, 0, stream>>>(feat, mean_enc);
    k_init_hc<<<(B * D) / 256, 256, 0, stream>>>(mean_enc, Wih_, bih, Wic, bic, xcat, c);
    k_init_inp<<<(B * EM) / 256, 256, 0, stream>>>(emb, xcat);
    k_packB2<<<(32 * KT * 64) / 256, 256, 0, stream>>>(Wea, Bh2, Bl2);
    k_packA2<<<((M_ROWS / 16) * KT * 64) / 256, 256, 0, stream>>>(feat, Ah2, Al2);
    k_att1_mfma<<<(M_ROWS / 64) * (AA / 128), 256, 0, stream>>>(Ah2, Al2, Bh2, Bl2, att1);

    for (int t = 0; t < TSTEPS; ++t) {
        k_ag<<<dim3(40, AGS), 256, 0, stream>>>(xcat, Wda, Wfb, bfb, agp);
        k_scores<<<(B * N) / 4, 256, 0, stream>>>(att1, agp, wfull, scores);
        k_awe<<<dim3(E / 1024, B), 256, 0, stream>>>(scores, feat, agp, xcat);
        k_z<<<dim3((4 * D) / 64, ZS1 + ZS2), 256, 0, stream>>>(xcat, Wih, Whh, zpart);
        k_lstm<<<(B * D / 4) / 256, 256, 0, stream>>>(zpart, blstm, c, xcat);
        k_preds<<<dim3((V + 63) / 64, PS), 256, 0, stream>>>(xcat, Wfc, bfc, predsp);
        k_argmax<<<B, 256, 0, stream>>>(predsp, emb, xcat, out, t);
    }
}